// Round 5
// baseline (85.462 us; speedup 1.0000x reference)
//
#include <hip/hip_runtime.h>

// DPConv (KERNEL=8, EXT=4, STRIDE=4) on (8,64,128,128) f32.
// K=16,k=8 -> adaptive bins degenerate to exact 2x2 pools; op is separable:
// vertical 4-tap then horizontal 4-tap, each with edge clamping:
//   U[h] = ( [h<124]*(x[max(h+m-4,0)] + x[max(h+m-3,0)])
//          + [h>=4 ]*(x[min(h+m,127)] + x[min(h+m+1,127)]) ) / (2*cnt),  m=h&3
// R4: LDS-free. One 32-lane group per image row; each lane owns 4 columns
// (c=4t..4t+3), computes the vertical tap in registers (M, float4), then the
// horizontal tap needs ONLY neighbor pair-sums:
//   s0=M.x+M.y, s1=M.z+M.w;  Ls*=lane t-1's s*, Rs*=lane t+1's s*
//   o = { f1*Ls0+f2*s0, f1*Ls1+f2*s1, f1*s0+f2*Rs0, f1*s1+f2*Rs1 } * sc
// with group-uniform f1=(t<31), f2=(t>0), sc=(t==0||t==31)?0.5:0.25 and
// edge broadcasts Ls*=2*M.x at t=0, Rs*=2*M.w at t=31 (cols -4,-3 clamp to 0).
// No LDS, no __syncthreads -> no barrier drain; occupancy VGPR-limited only.

#define HH 128
#define WW 128

__global__ __launch_bounds__(256) void dpconv_kernel(const float* __restrict__ x,
                                                     float* __restrict__ out) {
    const int gid = blockIdx.x * 256 + threadIdx.x;  // 512*128*32 threads
    const int t   = gid & 31;                        // column group (lane in 32-group)
    const int row = gid >> 5;                        // plane*128 + h
    const int h   = row & (HH - 1);

    const float* __restrict__ xp = x + (size_t)(row >> 7) * (HH * WW);
    float* __restrict__ op       = out + (size_t)row * WW;

    // ---- vertical 4-tap in registers ----
    const int m  = h & 3;
    const bool v1 = (h < 124);
    const bool v2 = (h >= 4);
    const int ra0 = max(h + m - 4, 0);
    const int ra1 = max(h + m - 3, 0);
    const int rb0 = min(h + m,     127);
    const int rb1 = min(h + m + 1, 127);
    const int c   = t << 2;

    const float4 a0 = *reinterpret_cast<const float4*>(xp + ra0 * WW + c);
    const float4 a1 = *reinterpret_cast<const float4*>(xp + ra1 * WW + c);
    const float4 b0 = *reinterpret_cast<const float4*>(xp + rb0 * WW + c);
    const float4 b1 = *reinterpret_cast<const float4*>(xp + rb1 * WW + c);

    const float g1 = v1 ? 1.0f : 0.0f;
    const float g2 = v2 ? 1.0f : 0.0f;
    const float gs = (v1 && v2) ? 0.25f : 0.5f;

    float4 M;
    M.x = (g1 * (a0.x + a1.x) + g2 * (b0.x + b1.x)) * gs;
    M.y = (g1 * (a0.y + a1.y) + g2 * (b0.y + b1.y)) * gs;
    M.z = (g1 * (a0.z + a1.z) + g2 * (b0.z + b1.z)) * gs;
    M.w = (g1 * (a0.w + a1.w) + g2 * (b0.w + b1.w)) * gs;

    // ---- horizontal 4-tap via neighbor pair-sums (width-32 shuffles) ----
    const float s0 = M.x + M.y;
    const float s1 = M.z + M.w;

    float Ls0 = __shfl_up(s0, 1, 32);
    float Ls1 = __shfl_up(s1, 1, 32);
    float Rs0 = __shfl_down(s0, 1, 32);
    float Rs1 = __shfl_down(s1, 1, 32);
    if (t == 0)  { Ls0 = 2.0f * M.x; Ls1 = 2.0f * M.x; }
    if (t == 31) { Rs0 = 2.0f * M.w; Rs1 = 2.0f * M.w; }

    const float f1 = (t < 31) ? 1.0f : 0.0f;   // w<124, uniform over group
    const float f2 = (t > 0)  ? 1.0f : 0.0f;   // w>=4,  uniform over group
    const float sc = (t == 0 || t == 31) ? 0.5f : 0.25f;

    float4 o;
    o.x = (f1 * Ls0 + f2 * s0) * sc;   // w = 4t+0
    o.y = (f1 * Ls1 + f2 * s1) * sc;   // w = 4t+1
    o.z = (f1 * s0 + f2 * Rs0) * sc;   // w = 4t+2
    o.w = (f1 * s1 + f2 * Rs1) * sc;   // w = 4t+3
    *reinterpret_cast<float4*>(op + c) = o;
}

extern "C" void kernel_launch(void* const* d_in, const int* in_sizes, int n_in,
                              void* d_out, int out_size, void* d_ws, size_t ws_size,
                              hipStream_t stream) {
    const float* x = (const float*)d_in[0];
    float* out     = (float*)d_out;
    const int planes  = in_sizes[0] / (HH * WW);       // 8*64 = 512
    const int threads = planes * HH * (WW / 4);        // one thread per 4 outputs
    dpconv_kernel<<<threads / 256, 256, 0, stream>>>(x, out);
}

// Round 10
// 80.202 us; speedup vs baseline: 1.0656x; 1.0656x over previous
//
#include <hip/hip_runtime.h>

// DPConv (KERNEL=8, EXT=4, STRIDE=4) on (8,64,128,128) f32.
// K=16,k=8 -> exact 2x2 pools; separable vertical+horizontal 4-tap with edge
// clamping (math verified R2-R5, refcheck passed):
//   U[h] = ( [h<124]*(x[max(h+m-4,0)]+x[max(h+m-3,0)])
//          + [h>=4 ]*(x[min(h+m,127)]+x[min(h+m+1,127)]) ) / (2*cnt),  m=h&3
// horizontal identical along W via neighbor pair-sums + width-32 shuffles.
//
// R6-R9: fix R5's diagnosed MLP deficit. Stage the RAW 40-row x tile into LDS
// with global_load_lds (16B, zero-VGPR async queue -> HBM-saturating
// outstanding bytes), one barrier, then R5's lean register compute reading
// 4x ds_read_b128 per item. LDS 20 KB -> 8 blocks/CU -> 32 waves/CU.

#define HH 128
#define WW 128
#define RCH 32
#define TROWS (RCH + 8)   // 4 halo rows each side

__global__ __launch_bounds__(256) void dpconv_kernel(const float* __restrict__ x,
                                                     float* __restrict__ out) {
    __shared__ float raw[TROWS][WW];   // 20480 B

    const int bid   = blockIdx.x;
    const int plane = bid >> 2;              // 4 chunks per plane
    const int h0    = (bid & 3) * RCH;

    const float* __restrict__ xp = x + (size_t)plane * (HH * WW);
    float* __restrict__ op       = out + (size_t)plane * (HH * WW) + (size_t)h0 * WW;

    // ---- stage raw x rows [h0-4, h0+36) (edge-clamped) into LDS ----
    // wave w stages rows w*10..w*10+9 as 5 instrs x 1024 B; HW dest = base + lane*16.
    const int wv = threadIdx.x >> 6;
    const int ln = threadIdx.x & 63;
#if __has_builtin(__builtin_amdgcn_global_load_lds)
    #pragma unroll
    for (int i = 0; i < 5; ++i) {
        const int row = wv * 10 + i * 2 + (ln >> 5);
        const int col = (ln & 31) << 2;
        const int gr  = min(max(h0 - 4 + row, 0), HH - 1);
        const float* src = xp + gr * WW + col;
        __builtin_amdgcn_global_load_lds(
            (__attribute__((address_space(1))) void*)src,
            (__attribute__((address_space(3))) void*)((char*)&raw[0][0] + wv * 5120 + i * 1024),
            16, 0, 0);
    }
#else
    for (int idx = threadIdx.x; idx < TROWS * 32; idx += 256) {
        const int row = idx >> 5;
        const int col = (idx & 31) << 2;
        const int gr  = min(max(h0 - 4 + row, 0), HH - 1);
        *reinterpret_cast<float4*>(&raw[row][col]) =
            *reinterpret_cast<const float4*>(xp + gr * WW + col);
    }
#endif
    __syncthreads();

    // ---- fused vertical(reg) + horizontal(shuffle) ----
    #pragma unroll
    for (int it = 0; it < 4; ++it) {
        const int e  = it * 256 + (int)threadIdx.x;
        const int hr = e >> 5;               // 0..31 output row in chunk
        const int t  = e & 31;               // column group, c = 4t
        const int h  = h0 + hr;
        const int m  = h & 3;
        const bool v1 = (h < 124);
        const bool v2 = (h >= 4);
        const int lbase = 4 - h0;            // local = clamped_global + lbase
        const int la0 = max(h + m - 4, 0) + lbase;
        const int la1 = max(h + m - 3, 0) + lbase;
        const int lb0 = min(h + m,     127) + lbase;
        const int lb1 = min(h + m + 1, 127) + lbase;
        const int c   = t << 2;

        const float4 a0 = *reinterpret_cast<const float4*>(&raw[la0][c]);
        const float4 a1 = *reinterpret_cast<const float4*>(&raw[la1][c]);
        const float4 b0 = *reinterpret_cast<const float4*>(&raw[lb0][c]);
        const float4 b1 = *reinterpret_cast<const float4*>(&raw[lb1][c]);

        const float g1 = v1 ? 1.0f : 0.0f;
        const float g2 = v2 ? 1.0f : 0.0f;
        const float gs = (v1 && v2) ? 0.25f : 0.5f;

        float4 M;
        M.x = (g1 * (a0.x + a1.x) + g2 * (b0.x + b1.x)) * gs;
        M.y = (g1 * (a0.y + a1.y) + g2 * (b0.y + b1.y)) * gs;
        M.z = (g1 * (a0.z + a1.z) + g2 * (b0.z + b1.z)) * gs;
        M.w = (g1 * (a0.w + a1.w) + g2 * (b0.w + b1.w)) * gs;

        const float s0 = M.x + M.y;
        const float s1 = M.z + M.w;

        float Ls0 = __shfl_up(s0, 1, 32);
        float Ls1 = __shfl_up(s1, 1, 32);
        float Rs0 = __shfl_down(s0, 1, 32);
        float Rs1 = __shfl_down(s1, 1, 32);
        if (t == 0)  { Ls0 = 2.0f * M.x; Ls1 = 2.0f * M.x; }
        if (t == 31) { Rs0 = 2.0f * M.w; Rs1 = 2.0f * M.w; }

        const float f1 = (t < 31) ? 1.0f : 0.0f;   // w<124, uniform over group
        const float f2 = (t > 0)  ? 1.0f : 0.0f;   // w>=4,  uniform over group
        const float sc = (t == 0 || t == 31) ? 0.5f : 0.25f;

        float4 o;
        o.x = (f1 * Ls0 + f2 * s0) * sc;   // w = 4t+0
        o.y = (f1 * Ls1 + f2 * s1) * sc;   // w = 4t+1
        o.z = (f1 * s0 + f2 * Rs0) * sc;   // w = 4t+2
        o.w = (f1 * s1 + f2 * Rs1) * sc;   // w = 4t+3
        *reinterpret_cast<float4*>(op + hr * WW + c) = o;
    }
}

extern "C" void kernel_launch(void* const* d_in, const int* in_sizes, int n_in,
                              void* d_out, int out_size, void* d_ws, size_t ws_size,
                              hipStream_t stream) {
    const float* x = (const float*)d_in[0];
    float* out     = (float*)d_out;
    const int planes = in_sizes[0] / (HH * WW);   // 8*64 = 512
    dpconv_kernel<<<planes * (HH / RCH), 256, 0, stream>>>(x, out);
}